// Round 9
// baseline (1037.002 us; speedup 1.0000x reference)
//
#include <hip/hip_runtime.h>
#include <hip/hip_cooperative_groups.h>

namespace cg = cooperative_groups;

#define N_NODES 100000
#define N_EDGES 1600000
#define D_IN    128
#define D_OUT   64

#define XT_STRIDE 260           // gemm LDS pad (proven)
#define NBUCKETS 1563           // ceil(100000/64) 64-row buckets
#define NBW 782                 // packed u16 words = ceil(NBUCKETS/2)
#define G2 1568                 // cnt/scatter slices = 8*196 (XCD-chunked)
#define SLICE2 1024             // edges per slice (4 tiles of 256)
#define M_FLAT (NBUCKETS * G2)  // 2,450,784 bucket-major count matrix
#define M_CHUNKS 2394           // ceil(M_FLAT/1024)
#define M_PAD (M_CHUNKS * 1024) // 2,451,456 (pad zeroed before scan)
#define GEMM_BLOCKS 391         // ceil(N_NODES/256)
#define CAP 2048                // LDS bucket-segment capacity (expected max ~1150)
typedef unsigned long long ull;
typedef unsigned int uint;

// ---------------------------------------------------------------------------
// Fused: support = X @ W (blocks 0..390, proven gemm) || bucket count
// (blocks 391.., proven cnt on hist aliased over gemm's LDS; 1568 slices
// of 1024 edges to match the cooperative middle's scatter slicing).
// ---------------------------------------------------------------------------
__global__ __launch_bounds__(256) void k_gemm_cnt(
    const float* __restrict__ x,        // [N, 128]
    const float* __restrict__ w,        // [128, 64]
    float* __restrict__ support,        // [N, 64]
    const int* __restrict__ rows,
    uint* __restrict__ S)
{
    __shared__ float wl[D_IN * D_OUT];      // 32 KB (cnt aliases hist here)
    __shared__ float xT[32 * XT_STRIDE];    // 33.3 KB

    const int t = threadIdx.x;

    if (blockIdx.x >= GEMM_BLOCKS) {
        // ---- count path ----
        uint* hist = (uint*)wl;             // NBW=782 u32 = 3.1 KB
        const int bid = blockIdx.x - GEMM_BLOCKS;
        const int b = (bid & 7) * 196 + (bid >> 3);  // chunked XCD swz
        for (int i = t; i < NBW; i += 256) hist[i] = 0u;
        // block 0 zeroes the scan pad tail (ws re-poisoned every replay)
        if (bid == 0)
            for (int i = t; i < M_PAD - M_FLAT; i += 256) S[M_FLAT + i] = 0u;
        __syncthreads();

        const int base = b * SLICE2;
#pragma unroll
        for (int s2 = 0; s2 < 4; ++s2) {
            const int e = base + s2 * 256 + t;
            if (e < N_EDGES) {
                const uint bk = (uint)rows[e] >> 6;
                atomicAdd(&hist[bk >> 1], 1u << ((bk & 1) * 16));
            }
        }
        __syncthreads();

        for (int i = t; i < NBUCKETS; i += 256)
            S[(size_t)i * G2 + b] = (hist[i >> 1] >> ((i & 1) * 16)) & 0xffffu;
        return;
    }

    // ---- gemm path (proven since round 0) ----
    const int tx = t & 7;
    const int ty = t >> 3;
    const long row0 = (long)blockIdx.x * 256;

    {
        const float4* wf  = (const float4*)w;
        float4*       wlf = (float4*)wl;
#pragma unroll
        for (int j = 0; j < 8; ++j)
            wlf[t + 256 * j] = wf[t + 256 * j];
    }

    float acc[8][8];
#pragma unroll
    for (int i = 0; i < 8; ++i)
#pragma unroll
        for (int j = 0; j < 8; ++j)
            acc[i][j] = 0.f;

    for (int kc = 0; kc < 4; ++kc) {
        const int k0 = kc * 32;
        __syncthreads();

        const int kk = tx * 4;
#pragma unroll
        for (int it = 0; it < 8; ++it) {
            const int  rg   = it * 32 + ty;
            const long grow = row0 + rg;
            float4 v = make_float4(0.f, 0.f, 0.f, 0.f);
            if (grow < N_NODES)
                v = *(const float4*)&x[grow * D_IN + k0 + kk];
            xT[(kk + 0) * XT_STRIDE + rg] = v.x;
            xT[(kk + 1) * XT_STRIDE + rg] = v.y;
            xT[(kk + 2) * XT_STRIDE + rg] = v.z;
            xT[(kk + 3) * XT_STRIDE + rg] = v.w;
        }
        __syncthreads();

#pragma unroll 8
        for (int k = 0; k < 32; ++k) {
            const float4 a0 = *(const float4*)&xT[k * XT_STRIDE + ty * 8];
            const float4 a1 = *(const float4*)&xT[k * XT_STRIDE + ty * 8 + 4];
            const float4 b0 = *(const float4*)&wl[(k0 + k) * D_OUT + tx * 8];
            const float4 b1 = *(const float4*)&wl[(k0 + k) * D_OUT + tx * 8 + 4];
            const float av[8] = {a0.x, a0.y, a0.z, a0.w, a1.x, a1.y, a1.z, a1.w};
            const float bv[8] = {b0.x, b0.y, b0.z, b0.w, b1.x, b1.y, b1.z, b1.w};
#pragma unroll
            for (int i = 0; i < 8; ++i)
#pragma unroll
                for (int j = 0; j < 8; ++j)
                    acc[i][j] = fmaf(av[i], bv[j], acc[i][j]);
        }
    }

#pragma unroll
    for (int i = 0; i < 8; ++i) {
        const long r = row0 + ty * 8 + i;
        if (r < N_NODES) {
            float4 o0 = make_float4(acc[i][0], acc[i][1], acc[i][2], acc[i][3]);
            float4 o1 = make_float4(acc[i][4], acc[i][5], acc[i][6], acc[i][7]);
            *(float4*)&support[r * D_OUT + tx * 8]     = o0;
            *(float4*)&support[r * D_OUT + tx * 8 + 4] = o1;
        }
    }
}

// ---------------------------------------------------------------------------
// k_mid: cooperative fusion of scanA + scanB + scatter + bucket.
// (Round-8 evidence: middle stuck at ~180us across 3 revisions while its
//  traffic is ~66MB (~11us at BW) -- overhead-bound: scatter at 1.5
//  blocks/CU had no latency hiding, scanB was a 1-block bubble, 4 launch
//  gaps. One cooperative launch, 1568 blocks * 8/CU-capable -> scatter at
//  ~6 blocks/CU, zero inter-phase launches.)
// LDS: shm (16KB) reused per phase: scanA scratch / scatter cur+bs / srt.
// __launch_bounds__(256,8): VGPR<=64 -> 8 blocks/CU -> coop capacity 2048.
// ---------------------------------------------------------------------------
__global__ __launch_bounds__(256, 8) void k_mid(
    uint* __restrict__ S, uint* __restrict__ bsum,
    const int* __restrict__ rows, const int* __restrict__ cols,
    const float* __restrict__ vals, const float* __restrict__ support,
    const float* __restrict__ prelu_a, float* __restrict__ out,
    ull* __restrict__ pairs)
{
    cg::grid_group grid = cg::this_grid();
    __shared__ ull  shm[CAP];               // 16 KB, phase-reused
    __shared__ uint meta[256];              // 1 KB scratch
    const int t = threadIdx.x;

    // ---- phase A: chunked exclusive scan of S (grid-stride) ----
    for (int chunk = blockIdx.x; chunk < M_CHUNKS; chunk += gridDim.x) {
        const size_t base = (size_t)chunk * 1024 + (size_t)t * 4;
        uint4 v = *(const uint4*)&S[base];          // pad zeroed by cnt
        const uint tsum = v.x + v.y + v.z + v.w;
        meta[t] = tsum;
        __syncthreads();
#pragma unroll
        for (int off = 1; off < 256; off <<= 1) {
            const uint add = (t >= off) ? meta[t - off] : 0u;
            __syncthreads();
            meta[t] += add;
            __syncthreads();
        }
        const uint eb = meta[t] - tsum;
        if (t == 255) bsum[chunk] = meta[255];
        uint4 o;
        o.x = eb; o.y = eb + v.x; o.z = o.y + v.y; o.w = o.z + v.z;
        *(uint4*)&S[base] = o;
        __syncthreads();                    // meta reuse next chunk
    }
    __threadfence();
    grid.sync();

    // ---- phase B: block 0 scans the chunk sums ----
    if (blockIdx.x == 0) {
        uint run = 0;
        for (int base = 0; base < M_CHUNKS; base += 256) {
            const int i = base + t;
            const uint v = (i < M_CHUNKS) ? bsum[i] : 0u;
            meta[t] = v;
            __syncthreads();
#pragma unroll
            for (int off = 1; off < 256; off <<= 1) {
                const uint add = (t >= off) ? meta[t - off] : 0u;
                __syncthreads();
                meta[t] += add;
                __syncthreads();
            }
            if (i < M_CHUNKS) bsum[i] = run + meta[t] - v;
            run += meta[255];
            __syncthreads();
        }
    }
    __threadfence();
    grid.sync();

    // ---- phase C: scatter (1568 slices of 1024 edges) ----
    {
        uint* cur = (uint*)shm;             // [NBUCKETS]
        uint* bs  = (uint*)shm + 1600;      // [M_CHUNKS]; 1600+2394 < 4096 u32
        const int b = (blockIdx.x & 7) * 196 + (blockIdx.x >> 3);
        for (int i = t; i < M_CHUNKS; i += 256) bs[i] = bsum[i];
        __syncthreads();
        for (int i = t; i < NBUCKETS; i += 256) {
            const size_t f = (size_t)i * G2 + b;
            cur[i] = S[f] + bs[f >> 10];
        }
        __syncthreads();

        const int base = b * SLICE2;
#pragma unroll
        for (int s2 = 0; s2 < 4; ++s2) {
            const int e = base + s2 * 256 + t;
            if (e < N_EDGES) {
                const uint r  = (uint)rows[e];
                const uint bk = r >> 6;
                const uint rl = r & 63u;
                const uint pos = atomicAdd(&cur[bk], 1u);
                pairs[pos] = ((ull)__float_as_uint(vals[e]) << 32)
                           | (rl << 17) | (uint)cols[e];
            }
        }
    }
    __threadfence();
    grid.sync();

    // ---- phase D: bucket aggregate (r8 proven logic) ----
    const int k = blockIdx.x;
    if (k < NBUCKETS) {
        ull*  srt    = shm;
        uint* h      = meta;                // carve 4x64 from meta
        uint* ex     = meta + 64;
        uint* rowoff = meta + 128;
        uint* cur    = meta + 192;
        const int w = t >> 6, lane = t & 63;

        const size_t f0 = (size_t)k * G2;
        const int beg = (int)(S[f0] + bsum[f0 >> 10]);
        int end;
        if (k == NBUCKETS - 1) end = N_EDGES;
        else {
            const size_t f1 = f0 + G2;
            end = (int)(S[f1] + bsum[f1 >> 10]);
        }
        const int n = end - beg;
        const float a = prelu_a[0];

        if (t < 64) h[t] = 0u;
        __syncthreads();

        if (n <= CAP) {
            // pass 1: hist (contiguous segment; warms L2)
            for (int i = t; i < n; i += 256)
                atomicAdd(&h[((uint)pairs[beg + i] >> 17) & 63u], 1u);
            __syncthreads();

            if (t < 64) ex[t] = h[t];
            __syncthreads();
#pragma unroll
            for (int off = 1; off < 64; off <<= 1) {
                const uint add = (t >= off && t < 64) ? ex[t - off] : 0u;
                __syncthreads();
                if (t < 64) ex[t] += add;
                __syncthreads();
            }
            if (t < 64) {
                rowoff[t] = ex[t] - h[t];
                cur[t]    = rowoff[t];
            }
            __syncthreads();

            // pass 2: re-read (L2-hot) + row-sort into LDS
            for (int i = t; i < n; i += 256) {
                const ull p = pairs[beg + i];
                const uint pos = atomicAdd(&cur[((uint)p >> 17) & 63u], 1u);
                srt[pos] = p;
            }
            __syncthreads();

            // rowsum: wave w owns rows w*16 .. w*16+15 of this bucket
            for (int q = 0; q < 16; ++q) {
                const int rl  = w * 16 + q;
                const long row = (long)k * 64 + rl;
                if (row >= N_NODES) break;
                const int st  = (int)rowoff[rl];
                const int deg = (int)h[rl];

                float acc = 0.f;
                int j = 0;
                for (; j + 8 <= deg; j += 8) {
                    ull p[8];
#pragma unroll
                    for (int u = 0; u < 8; ++u) p[u] = srt[st + j + u];
                    float sv[8];
#pragma unroll
                    for (int u = 0; u < 8; ++u)
                        sv[u] = support[(size_t)((uint)p[u] & 0x1ffffu) * D_OUT + lane];
#pragma unroll
                    for (int u = 0; u < 8; ++u)
                        acc = fmaf(__uint_as_float((uint)(p[u] >> 32)), sv[u], acc);
                }
                for (; j + 4 <= deg; j += 4) {
                    ull p[4];
#pragma unroll
                    for (int u = 0; u < 4; ++u) p[u] = srt[st + j + u];
                    float sv[4];
#pragma unroll
                    for (int u = 0; u < 4; ++u)
                        sv[u] = support[(size_t)((uint)p[u] & 0x1ffffu) * D_OUT + lane];
#pragma unroll
                    for (int u = 0; u < 4; ++u)
                        acc = fmaf(__uint_as_float((uint)(p[u] >> 32)), sv[u], acc);
                }
                for (; j < deg; ++j) {
                    const ull p = srt[st + j];
                    acc = fmaf(__uint_as_float((uint)(p >> 32)),
                               support[(size_t)((uint)p & 0x1ffffu) * D_OUT + lane], acc);
                }
                out[row * D_OUT + lane] = acc > 0.f ? acc : a * acc;
            }
        } else {
            // never expected (n <= ~1150); correct slow path
            for (int q = 0; q < 16; ++q) {
                const int rl  = w * 16 + q;
                const long row = (long)k * 64 + rl;
                if (row >= N_NODES) break;
                float acc = 0.f;
                for (int i = 0; i < n; ++i) {
                    const ull p = pairs[beg + i];
                    if ((((uint)p >> 17) & 63u) == (uint)rl)
                        acc = fmaf(__uint_as_float((uint)(p >> 32)),
                                   support[(size_t)((uint)p & 0x1ffffu) * D_OUT + lane],
                                   acc);
                }
                out[row * D_OUT + lane] = acc > 0.f ? acc : a * acc;
            }
        }
    }
}

// ---------------------------------------------------------------------------
extern "C" void kernel_launch(void* const* d_in, const int* in_sizes, int n_in,
                              void* d_out, int out_size, void* d_ws, size_t ws_size,
                              hipStream_t stream) {
    const float* x    = (const float*)d_in[0];
    const int*   rows = (const int*)d_in[1];
    const int*   cols = (const int*)d_in[2];
    const float* vals = (const float*)d_in[3];
    const float* w    = (const float*)d_in[4];
    const float* pa   = (const float*)d_in[5];

    float* out     = (float*)d_out;                    // [N*64] PReLU output
    float* support = out + (size_t)N_NODES * D_OUT;    // [N*64] support (tuple elem 1)

    // workspace layout (~22.6 MiB)
    uint* S    = (uint*)d_ws;                          // M_PAD u32 = 9.8 MB
    uint* bsum = S + (size_t)M_PAD;                    // 2560 u32
    // byte offset of pairs: (2451456+2560)*4 = 9,816,064 (8B-aligned)
    ull*  pairs = (ull*)(bsum + 2560);                 // 1.6M x 8B

    k_gemm_cnt<<<GEMM_BLOCKS + G2, 256, 0, stream>>>(x, w, support, rows, S);

    void* args[] = { (void*)&S, (void*)&bsum, (void*)&rows, (void*)&cols,
                     (void*)&vals, (void*)&support, (void*)&pa, (void*)&out,
                     (void*)&pairs };
    hipLaunchCooperativeKernel((void*)k_mid, dim3(G2), dim3(256), args, 0, stream);
}

// Round 10
// 229.242 us; speedup vs baseline: 4.5236x; 4.5236x over previous
//
#include <hip/hip_runtime.h>

#define N_NODES 100000
#define N_EDGES 1600000
#define D_IN    128
#define D_OUT   64

#define XT_STRIDE 260           // gemm LDS pad (proven)
#define NBUCKETS 1563           // ceil(100000/64) 64-row buckets
#define NBW 782                 // packed u16 words = ceil(NBUCKETS/2)
#define G 392                   // scatter/count blocks = 8*49 (XCD-chunked)
#define SLICE 4096              // edges per count/scatter block
#define M_FLAT (NBUCKETS * G)   // 612,696 (bucket-major count matrix)
#define SCANA_BLOCKS 599        // ceil(M_FLAT/1024)
#define GEMM_BLOCKS 391         // ceil(N_NODES/256)
#define CAP 2048                // LDS bucket-segment capacity (expected max ~1150)
typedef unsigned long long ull;
typedef unsigned int uint;

// ---------------------------------------------------------------------------
// Fused: support = X @ W (blocks 0..390, proven gemm) || bucket count
// (blocks 391..782, proven cnt; now int4-vectorized rows reads).
// ---------------------------------------------------------------------------
__global__ __launch_bounds__(256) void k_gemm_cnt(
    const float* __restrict__ x,        // [N, 128]
    const float* __restrict__ w,        // [128, 64]
    float* __restrict__ support,        // [N, 64]
    const int* __restrict__ rows,
    uint* __restrict__ S)
{
    __shared__ float wl[D_IN * D_OUT];      // 32 KB (cnt aliases hist here)
    __shared__ float xT[32 * XT_STRIDE];    // 33.3 KB

    const int t = threadIdx.x;

    if (blockIdx.x >= GEMM_BLOCKS) {
        // ---- count path ----
        uint* hist = (uint*)wl;             // NBW=782 u32 = 3.1 KB
        const int bid = blockIdx.x - GEMM_BLOCKS;
        const int b = (bid & 7) * 49 + (bid >> 3);  // chunked XCD swz
        for (int i = t; i < NBW; i += 256) hist[i] = 0u;
        __syncthreads();

        const int base = b * SLICE;
#pragma unroll
        for (int s2 = 0; s2 < 4; ++s2) {
            const int e = base + s2 * 1024 + t * 4;     // 16B-aligned
            if (e < N_EDGES) {                          // N%4==0 -> full int4
                const int4 r4 = *(const int4*)&rows[e];
                atomicAdd(&hist[(uint)r4.x >> 7], 1u << ((((uint)r4.x >> 6) & 1) * 16));
                atomicAdd(&hist[(uint)r4.y >> 7], 1u << ((((uint)r4.y >> 6) & 1) * 16));
                atomicAdd(&hist[(uint)r4.z >> 7], 1u << ((((uint)r4.z >> 6) & 1) * 16));
                atomicAdd(&hist[(uint)r4.w >> 7], 1u << ((((uint)r4.w >> 6) & 1) * 16));
            }
        }
        __syncthreads();

        for (int i = t; i < NBUCKETS; i += 256)
            S[(size_t)i * G + b] = (hist[i >> 1] >> ((i & 1) * 16)) & 0xffffu;
        return;
    }

    // ---- gemm path (proven since round 0) ----
    const int tx = t & 7;
    const int ty = t >> 3;
    const long row0 = (long)blockIdx.x * 256;

    {
        const float4* wf  = (const float4*)w;
        float4*       wlf = (float4*)wl;
#pragma unroll
        for (int j = 0; j < 8; ++j)
            wlf[t + 256 * j] = wf[t + 256 * j];
    }

    float acc[8][8];
#pragma unroll
    for (int i = 0; i < 8; ++i)
#pragma unroll
        for (int j = 0; j < 8; ++j)
            acc[i][j] = 0.f;

    for (int kc = 0; kc < 4; ++kc) {
        const int k0 = kc * 32;
        __syncthreads();

        const int kk = tx * 4;
#pragma unroll
        for (int it = 0; it < 8; ++it) {
            const int  rg   = it * 32 + ty;
            const long grow = row0 + rg;
            float4 v = make_float4(0.f, 0.f, 0.f, 0.f);
            if (grow < N_NODES)
                v = *(const float4*)&x[grow * D_IN + k0 + kk];
            xT[(kk + 0) * XT_STRIDE + rg] = v.x;
            xT[(kk + 1) * XT_STRIDE + rg] = v.y;
            xT[(kk + 2) * XT_STRIDE + rg] = v.z;
            xT[(kk + 3) * XT_STRIDE + rg] = v.w;
        }
        __syncthreads();

#pragma unroll 8
        for (int k = 0; k < 32; ++k) {
            const float4 a0 = *(const float4*)&xT[k * XT_STRIDE + ty * 8];
            const float4 a1 = *(const float4*)&xT[k * XT_STRIDE + ty * 8 + 4];
            const float4 b0 = *(const float4*)&wl[(k0 + k) * D_OUT + tx * 8];
            const float4 b1 = *(const float4*)&wl[(k0 + k) * D_OUT + tx * 8 + 4];
            const float av[8] = {a0.x, a0.y, a0.z, a0.w, a1.x, a1.y, a1.z, a1.w};
            const float bv[8] = {b0.x, b0.y, b0.z, b0.w, b1.x, b1.y, b1.z, b1.w};
#pragma unroll
            for (int i = 0; i < 8; ++i)
#pragma unroll
                for (int j = 0; j < 8; ++j)
                    acc[i][j] = fmaf(av[i], bv[j], acc[i][j]);
        }
    }

#pragma unroll
    for (int i = 0; i < 8; ++i) {
        const long r = row0 + ty * 8 + i;
        if (r < N_NODES) {
            float4 o0 = make_float4(acc[i][0], acc[i][1], acc[i][2], acc[i][3]);
            float4 o1 = make_float4(acc[i][4], acc[i][5], acc[i][6], acc[i][7]);
            *(float4*)&support[r * D_OUT + tx * 8]     = o0;
            *(float4*)&support[r * D_OUT + tx * 8 + 4] = o1;
        }
    }
}

// ---------------------------------------------------------------------------
// k_scanA: per-1024-chunk exclusive scan of bucket-major S; bsum[chunk] gets
// the chunk TOTAL (scanned locally by consumers -- scanB launch deleted).
// ---------------------------------------------------------------------------
__global__ __launch_bounds__(256) void k_scanA(
    uint* __restrict__ S, uint* __restrict__ bsum)
{
    __shared__ uint s[256];
    const int t = threadIdx.x;
    const size_t base = (size_t)blockIdx.x * 1024 + (size_t)t * 4;
    uint4 v = make_uint4(0u, 0u, 0u, 0u);
    if (base < M_FLAT) v = *(const uint4*)&S[base];   // M_FLAT%4==0
    const uint tsum = v.x + v.y + v.z + v.w;
    s[t] = tsum;
    __syncthreads();
#pragma unroll
    for (int off = 1; off < 256; off <<= 1) {
        const uint add = (t >= off) ? s[t - off] : 0u;
        __syncthreads();
        s[t] += add;
        __syncthreads();
    }
    const uint eb = s[t] - tsum;
    if (t == 255) bsum[blockIdx.x] = s[255];          // chunk total
    if (base < M_FLAT) {
        uint4 o;
        o.x = eb; o.y = eb + v.x; o.z = o.y + v.y; o.w = o.z + v.z;
        *(uint4*)&S[base] = o;
    }
}

// ---------------------------------------------------------------------------
// k_scatter: block b seeds LDS cursors from S + locally-scanned bsum, then
// scatters its 4096-edge slice (int4/float4 vectorized). Block bid==0 also
// publishes the scanned chunk-prefix to bsum2 for k_bucket (next launch).
// ---------------------------------------------------------------------------
__global__ __launch_bounds__(256) void k_scatter(
    const int* __restrict__ rows, const int* __restrict__ cols,
    const float* __restrict__ vals, const uint* __restrict__ S,
    const uint* __restrict__ bsum, uint* __restrict__ bsum2,
    ull* __restrict__ pairs)
{
    __shared__ uint cur[NBUCKETS];          // 6.25 KB
    __shared__ uint bs[SCANA_BLOCKS];       // 2.4 KB
    __shared__ uint meta[256];              // 1 KB scan scratch
    const int t = threadIdx.x;
    const int bid = blockIdx.x;
    const int b = (bid & 7) * 49 + (bid >> 3);

    for (int i = t; i < SCANA_BLOCKS; i += 256) bs[i] = bsum[i];
    __syncthreads();

    // local exclusive scan of the 599 chunk totals (3 rounds of 256)
    uint carry = 0;
    for (int c0 = 0; c0 < SCANA_BLOCKS; c0 += 256) {
        const int i = c0 + t;
        const uint v = (i < SCANA_BLOCKS) ? bs[i] : 0u;
        meta[t] = v;
        __syncthreads();
#pragma unroll
        for (int off = 1; off < 256; off <<= 1) {
            const uint add = (t >= off) ? meta[t - off] : 0u;
            __syncthreads();
            meta[t] += add;
            __syncthreads();
        }
        if (i < SCANA_BLOCKS) bs[i] = carry + meta[t] - v;
        carry += meta[255];
        __syncthreads();
    }
    if (bid == 0)
        for (int i = t; i < SCANA_BLOCKS; i += 256) bsum2[i] = bs[i];

    for (int i = t; i < NBUCKETS; i += 256) {
        const size_t f = (size_t)i * G + b;
        cur[i] = S[f] + bs[f >> 10];
    }
    __syncthreads();

    const int base = b * SLICE;
#pragma unroll
    for (int s2 = 0; s2 < 4; ++s2) {
        const int e = base + s2 * 1024 + t * 4;     // 16B-aligned
        if (e < N_EDGES) {                          // N%4==0 -> full vectors
            const int4   r4 = *(const int4*)&rows[e];
            const int4   c4 = *(const int4*)&cols[e];
            const float4 v4 = *(const float4*)&vals[e];
            {
                const uint r = (uint)r4.x;
                const uint pos = atomicAdd(&cur[r >> 6], 1u);
                pairs[pos] = ((ull)__float_as_uint(v4.x) << 32)
                           | ((r & 63u) << 17) | (uint)c4.x;
            }
            {
                const uint r = (uint)r4.y;
                const uint pos = atomicAdd(&cur[r >> 6], 1u);
                pairs[pos] = ((ull)__float_as_uint(v4.y) << 32)
                           | ((r & 63u) << 17) | (uint)c4.y;
            }
            {
                const uint r = (uint)r4.z;
                const uint pos = atomicAdd(&cur[r >> 6], 1u);
                pairs[pos] = ((ull)__float_as_uint(v4.z) << 32)
                           | ((r & 63u) << 17) | (uint)c4.z;
            }
            {
                const uint r = (uint)r4.w;
                const uint pos = atomicAdd(&cur[r >> 6], 1u);
                pairs[pos] = ((ull)__float_as_uint(v4.w) << 32)
                           | ((r & 63u) << 17) | (uint)c4.w;
            }
        }
    }
}

// ---------------------------------------------------------------------------
// k_bucket: one block per 64-row bucket (r8 proven: 62us, 3.3 TB/s, 53% occ).
// Pass 1: hist (ds_add_u32) over the contiguous segment. 64-scan. Pass 2:
// re-read (L2-hot) + row-sort into LDS. Then 4 waves x 16 rows run the
// lane=col 8-deep gather rowsum + fused PReLU. No fp atomics.
// ---------------------------------------------------------------------------
__global__ __launch_bounds__(256) void k_bucket(
    const uint* __restrict__ S, const uint* __restrict__ bsum2,
    const ull* __restrict__ pairs, const float* __restrict__ support,
    const float* __restrict__ prelu_a, float* __restrict__ out)
{
    __shared__ ull srt[CAP];                // 16 KB
    __shared__ uint h[64], ex[64], rowoff[64], cur[64];
    const int k = blockIdx.x;
    const int t = threadIdx.x, w = t >> 6, lane = t & 63;

    const size_t f0 = (size_t)k * G;
    const int beg = (int)(S[f0] + bsum2[f0 >> 10]);
    int end;
    if (k == NBUCKETS - 1) end = N_EDGES;
    else {
        const size_t f1 = f0 + G;
        end = (int)(S[f1] + bsum2[f1 >> 10]);
    }
    const int n = end - beg;
    const float a = prelu_a[0];

    if (t < 64) h[t] = 0u;
    __syncthreads();

    if (n <= CAP) {
        // pass 1: hist (contiguous segment; warms L2)
        for (int i = t; i < n; i += 256)
            atomicAdd(&h[((uint)pairs[beg + i] >> 17) & 63u], 1u);
        __syncthreads();

        if (t < 64) ex[t] = h[t];
        __syncthreads();
#pragma unroll
        for (int off = 1; off < 64; off <<= 1) {
            const uint add = (t >= off && t < 64) ? ex[t - off] : 0u;
            __syncthreads();
            if (t < 64) ex[t] += add;
            __syncthreads();
        }
        if (t < 64) {
            rowoff[t] = ex[t] - h[t];
            cur[t]    = rowoff[t];
        }
        __syncthreads();

        // pass 2: re-read (L2-hot) + row-sort into LDS
        for (int i = t; i < n; i += 256) {
            const ull p = pairs[beg + i];
            const uint pos = atomicAdd(&cur[((uint)p >> 17) & 63u], 1u);
            srt[pos] = p;
        }
        __syncthreads();

        // rowsum: wave w owns rows w*16 .. w*16+15 of this bucket
        for (int q = 0; q < 16; ++q) {
            const int rl  = w * 16 + q;
            const long row = (long)k * 64 + rl;
            if (row >= N_NODES) break;
            const int st  = (int)rowoff[rl];
            const int deg = (int)h[rl];

            float acc = 0.f;
            int j = 0;
            for (; j + 8 <= deg; j += 8) {
                ull p[8];
#pragma unroll
                for (int u = 0; u < 8; ++u) p[u] = srt[st + j + u];
                float sv[8];
#pragma unroll
                for (int u = 0; u < 8; ++u)
                    sv[u] = support[(size_t)((uint)p[u] & 0x1ffffu) * D_OUT + lane];
#pragma unroll
                for (int u = 0; u < 8; ++u)
                    acc = fmaf(__uint_as_float((uint)(p[u] >> 32)), sv[u], acc);
            }
            for (; j + 4 <= deg; j += 4) {
                ull p[4];
#pragma unroll
                for (int u = 0; u < 4; ++u) p[u] = srt[st + j + u];
                float sv[4];
#pragma unroll
                for (int u = 0; u < 4; ++u)
                    sv[u] = support[(size_t)((uint)p[u] & 0x1ffffu) * D_OUT + lane];
#pragma unroll
                for (int u = 0; u < 4; ++u)
                    acc = fmaf(__uint_as_float((uint)(p[u] >> 32)), sv[u], acc);
            }
            for (; j < deg; ++j) {
                const ull p = srt[st + j];
                acc = fmaf(__uint_as_float((uint)(p >> 32)),
                           support[(size_t)((uint)p & 0x1ffffu) * D_OUT + lane], acc);
            }
            out[row * D_OUT + lane] = acc > 0.f ? acc : a * acc;
        }
    } else {
        // never expected (n <= ~1150); correct slow path
        for (int q = 0; q < 16; ++q) {
            const int rl  = w * 16 + q;
            const long row = (long)k * 64 + rl;
            if (row >= N_NODES) break;
            float acc = 0.f;
            for (int i = 0; i < n; ++i) {
                const ull p = pairs[beg + i];
                if ((((uint)p >> 17) & 63u) == (uint)rl)
                    acc = fmaf(__uint_as_float((uint)(p >> 32)),
                               support[(size_t)((uint)p & 0x1ffffu) * D_OUT + lane],
                               acc);
            }
            out[row * D_OUT + lane] = acc > 0.f ? acc : a * acc;
        }
    }
}

// ---------------------------------------------------------------------------
extern "C" void kernel_launch(void* const* d_in, const int* in_sizes, int n_in,
                              void* d_out, int out_size, void* d_ws, size_t ws_size,
                              hipStream_t stream) {
    const float* x    = (const float*)d_in[0];
    const int*   rows = (const int*)d_in[1];
    const int*   cols = (const int*)d_in[2];
    const float* vals = (const float*)d_in[3];
    const float* w    = (const float*)d_in[4];
    const float* pa   = (const float*)d_in[5];

    float* out     = (float*)d_out;                    // [N*64] PReLU output
    float* support = out + (size_t)N_NODES * D_OUT;    // [N*64] support (tuple elem 1)

    // workspace layout (~15.3 MiB)
    uint* S     = (uint*)d_ws;                         // 599*1024 u32
    uint* bsum  = S + (size_t)SCANA_BLOCKS * 1024;     // 1024 u32 (chunk totals)
    uint* bsum2 = bsum + 1024;                         // 1024 u32 (scanned prefix)
    // byte offset of pairs: (613376+2048)*4 = 2,461,696 (8B-aligned)
    ull*  pairs = (ull*)(bsum2 + 1024);                // 1.6M x 8B

    k_gemm_cnt<<<GEMM_BLOCKS + G, 256, 0, stream>>>(x, w, support, rows, S);
    k_scanA   <<<SCANA_BLOCKS, 256, 0, stream>>>(S, bsum);
    k_scatter <<<G, 256, 0, stream>>>(rows, cols, vals, S, bsum, bsum2, pairs);
    k_bucket  <<<NBUCKETS, 256, 0, stream>>>(S, bsum2, pairs, support, pa, out);
}